// Round 5
// baseline (32078.320 us; speedup 1.0000x reference)
//
#include <hip/hip_runtime.h>
#include <math.h>

// h_t = tanh(A h_{t-1} + B x_t + c), A = 0.9 I + 0.1 A_raw
// T=16384, X=512, H=1024, fp32. Output: all h_t, [T, H].
//
// Phase 1: Bx = x @ B^T + c written in-place into d_out (row t consumed
//          exactly once at step t, then overwritten with h_t).
// Phase 2: barrier-free tagged-slot pipeline, PER-WAVE direct gather:
//   - 64 blocks x 256 threads = 256 waves; wave g (global id) owns rows
//     4g..4g+3. A rows in registers (float2 aw[4][8] per lane).
//   - h_t element j is an 8B (value, tag=t+1) packet in a 4-deep ring of
//     1024-slot buffers (h_t -> ring[t&3]); h0 tag 0 in ring[3]. Tags make
//     stale data self-identifying: NO grid barrier, NO __syncthreads, NO
//     LDS broadcast. Each wave gathers ALL 1024 packets itself: 8 x
//     global_load_dwordx4 sc0 sc1 per lane (inline asm - the compiler
//     refuses to batch atomic loads, measured rounds 1-2), one vmcnt(0),
//     check 16 tags, retry. One LLC round trip per poll iteration.
//   - Skew between any two waves <= 1 step by dataflow (step t+1 requires
//     all rows of step t), so a 4-deep ring never overwrites live data.
//   - Lane layout: lane l, load j covers packets j*128+2l, j*128+2l+1.
//   - Epilogue: 4 butterfly reductions, branchless exp/rcp tanh on all
//     lanes (lane&3 selects row), masked 16B packet stores (lanes 0,2),
//     masked out[] stores (lanes 0..3). Bx prefetched one step ahead.

#define T_STEPS 16384
#define XD 512
#define HD 1024

typedef unsigned int uint32x4 __attribute__((ext_vector_type(4)));

union fu { float f; unsigned u; };

__device__ __forceinline__ float fast_tanh(float x) {
    // tanh(x) = 1 - 2/(exp(2x)+1); v_exp + v_rcp, branchless, ~1e-7 abs err.
    // Overflow x>+44: e=inf -> rcp=0 -> 1. Underflow: e=0 -> -1. Graceful.
    const float e = __expf(2.0f * x);
    return 1.0f - 2.0f * __builtin_amdgcn_rcpf(e + 1.0f);
}

// ---------------------------------------------------------------------------
// Phase 1: GEMM  out[t][i] = sum_k x[t][k] * B[i][k] + c[i]
// 64x64 tile, 256 threads, 4x4 micro-tile per thread, K-chunk 32.
// ---------------------------------------------------------------------------
__global__ __launch_bounds__(256) void gemm_bx_kernel(
    const float* __restrict__ x, const float* __restrict__ B,
    const float* __restrict__ c, float* __restrict__ out)
{
    __shared__ __align__(16) float xs[32][68];  // [k][t]
    __shared__ __align__(16) float bs[32][68];  // [k][i]

    const int tid = threadIdx.x;
    const int t0 = blockIdx.x * 64;
    const int i0 = blockIdx.y * 64;
    const int tx = tid & 15;        // i direction (4 outputs)
    const int ty = tid >> 4;        // t direction (4 outputs)
    const int lr = tid >> 3;        // staging row 0..31
    const int lc = (tid & 7) << 2;  // staging k 0,4,...,28

    float acc[4][4] = {{0.f}};

    for (int k0 = 0; k0 < XD; k0 += 32) {
        const float4 xa = *(const float4*)&x[(size_t)(t0 + lr) * XD + k0 + lc];
        const float4 xb = *(const float4*)&x[(size_t)(t0 + lr + 32) * XD + k0 + lc];
        const float4 ba = *(const float4*)&B[(size_t)(i0 + lr) * XD + k0 + lc];
        const float4 bb = *(const float4*)&B[(size_t)(i0 + lr + 32) * XD + k0 + lc];
        __syncthreads();
        xs[lc + 0][lr] = xa.x; xs[lc + 1][lr] = xa.y; xs[lc + 2][lr] = xa.z; xs[lc + 3][lr] = xa.w;
        xs[lc + 0][lr + 32] = xb.x; xs[lc + 1][lr + 32] = xb.y; xs[lc + 2][lr + 32] = xb.z; xs[lc + 3][lr + 32] = xb.w;
        bs[lc + 0][lr] = ba.x; bs[lc + 1][lr] = ba.y; bs[lc + 2][lr] = ba.z; bs[lc + 3][lr] = ba.w;
        bs[lc + 0][lr + 32] = bb.x; bs[lc + 1][lr + 32] = bb.y; bs[lc + 2][lr + 32] = bb.z; bs[lc + 3][lr + 32] = bb.w;
        __syncthreads();
        #pragma unroll
        for (int k = 0; k < 32; ++k) {
            const float4 av = *(const float4*)&xs[k][ty << 2];
            const float4 bv = *(const float4*)&bs[k][tx << 2];
            const float am[4] = {av.x, av.y, av.z, av.w};
            const float bn[4] = {bv.x, bv.y, bv.z, bv.w};
            #pragma unroll
            for (int m = 0; m < 4; ++m)
                #pragma unroll
                for (int n = 0; n < 4; ++n)
                    acc[m][n] = fmaf(am[m], bn[n], acc[m][n]);
        }
    }

    #pragma unroll
    for (int m = 0; m < 4; ++m) {
        const int trow = t0 + (ty << 2) + m;
        #pragma unroll
        for (int n = 0; n < 4; ++n) {
            const int icol = i0 + (tx << 2) + n;
            out[(size_t)trow * HD + icol] = acc[m][n] + c[icol];
        }
    }
}

// ---------------------------------------------------------------------------
// Slot-ring init (d_ws is poisoned 0xAA before every launch).
// ring[3] holds h0 with tag 0; rings 0..2 get an impossible tag.
// ---------------------------------------------------------------------------
__global__ void init_slots_kernel(unsigned long long* slots, const float* h0)
{
    const int i = threadIdx.x;  // 1024 threads
    fu v; v.f = h0[i];
    slots[3 * HD + i] = (unsigned long long)v.u;          // tag 0 | h0 bits
    slots[0 * HD + i] = 0xFFFFFFFF00000000ull;
    slots[1 * HD + i] = 0xFFFFFFFF00000000ull;
    slots[2 * HD + i] = 0xFFFFFFFF00000000ull;
}

// ---------------------------------------------------------------------------
// Phase 2: tagged-slot scan, per-wave gather. 64 blocks x 256 threads.
// Global wave g = blockIdx.x*4 + (tid>>6) owns rows 4g..4g+3.
// ---------------------------------------------------------------------------
__global__ __launch_bounds__(256) void rnn_scan_kernel(
    const float* __restrict__ A_raw, float* __restrict__ out,
    unsigned long long* slots)
{
    const int tid = threadIdx.x;
    const int wave = tid >> 6;
    const int lane = tid & 63;
    const int wid = blockIdx.x * 4 + wave;    // 0..255
    const int r0 = wid << 2;                  // rows r0..r0+3
    const int sel = lane & 3;

    // A_eff[r][k] = 0.1*A_raw[r][k] + 0.9*(k==r).
    // aw[rr][j] covers k = j*128 + 2*lane (+0, +1).
    float2 aw[4][8];
    #pragma unroll
    for (int rr = 0; rr < 4; ++rr) {
        const int r = r0 + rr;
        #pragma unroll
        for (int j = 0; j < 8; ++j) {
            const int k = j * 128 + 2 * lane;
            float v0 = 0.1f * A_raw[(size_t)r * HD + k];
            float v1 = 0.1f * A_raw[(size_t)r * HD + k + 1];
            if (k == r)     v0 += 0.9f;
            if (k + 1 == r) v1 += 0.9f;
            aw[rr][j] = make_float2(v0, v1);
        }
    }

    // Prefetch Bx for t=0: lane handles row r0+sel.
    float bx = out[r0 + sel];

    for (int t = 0; t < T_STEPS; ++t) {
        const unsigned tagw = (unsigned)t;
        const char* base0 = (const char*)slots + (((t + 3) & 3) << 13) + (lane << 4);
        const char* base1 = base0 + 4096;

        uint32x4 s0, s1, s2, s3, s4, s5, s6, s7;
        unsigned bad;
        do {
            asm volatile(
                "global_load_dwordx4 %0, %[a0], off sc0 sc1\n\t"
                "global_load_dwordx4 %1, %[a0], off offset:1024 sc0 sc1\n\t"
                "global_load_dwordx4 %2, %[a0], off offset:2048 sc0 sc1\n\t"
                "global_load_dwordx4 %3, %[a0], off offset:3072 sc0 sc1\n\t"
                "global_load_dwordx4 %4, %[a1], off sc0 sc1\n\t"
                "global_load_dwordx4 %5, %[a1], off offset:1024 sc0 sc1\n\t"
                "global_load_dwordx4 %6, %[a1], off offset:2048 sc0 sc1\n\t"
                "global_load_dwordx4 %7, %[a1], off offset:3072 sc0 sc1\n\t"
                "s_waitcnt vmcnt(0)"
                : "=v"(s0), "=v"(s1), "=v"(s2), "=v"(s3),
                  "=v"(s4), "=v"(s5), "=v"(s6), "=v"(s7)
                : [a0] "v"(base0), [a1] "v"(base1));
            bad  = (s0.y ^ tagw) | (s0.w ^ tagw);
            bad |= (s1.y ^ tagw) | (s1.w ^ tagw);
            bad |= (s2.y ^ tagw) | (s2.w ^ tagw);
            bad |= (s3.y ^ tagw) | (s3.w ^ tagw);
            bad |= (s4.y ^ tagw) | (s4.w ^ tagw);
            bad |= (s5.y ^ tagw) | (s5.w ^ tagw);
            bad |= (s6.y ^ tagw) | (s6.w ^ tagw);
            bad |= (s7.y ^ tagw) | (s7.w ^ tagw);
        } while (__any((int)bad));

        // Prefetch next step's Bx (independent of the gather).
        const int tn = (t + 1 < T_STEPS) ? (t + 1) : t;
        const float bx_next = out[(size_t)tn * HD + r0 + sel];

        // 4 row partial dot products (64 fma/lane).
        float p0 = 0.f, p1 = 0.f, p2 = 0.f, p3 = 0.f;
        #define ACC(S, J) { fu a_, b_; a_.u = S.x; b_.u = S.z;                 \
            p0 = fmaf(aw[0][J].x, a_.f, fmaf(aw[0][J].y, b_.f, p0));           \
            p1 = fmaf(aw[1][J].x, a_.f, fmaf(aw[1][J].y, b_.f, p1));           \
            p2 = fmaf(aw[2][J].x, a_.f, fmaf(aw[2][J].y, b_.f, p2));           \
            p3 = fmaf(aw[3][J].x, a_.f, fmaf(aw[3][J].y, b_.f, p3)); }
        ACC(s0, 0) ACC(s1, 1) ACC(s2, 2) ACC(s3, 3)
        ACC(s4, 4) ACC(s5, 5) ACC(s6, 6) ACC(s7, 7)
        #undef ACC

        // Wave-wide sums (all lanes end with all 4 totals).
        #pragma unroll
        for (int off = 32; off >= 1; off >>= 1) {
            p0 += __shfl_xor(p0, off, 64);
            p1 += __shfl_xor(p1, off, 64);
            p2 += __shfl_xor(p2, off, 64);
            p3 += __shfl_xor(p3, off, 64);
        }

        const float p = (sel == 0) ? p0 : (sel == 1) ? p1 : (sel == 2) ? p2 : p3;
        const float h = fast_tanh(p + bx);

        // out[t][r0..r0+3]: lanes 0..3 store one float each (one instr).
        if (lane < 4)
            out[(size_t)t * HD + r0 + lane] = h;

        // Packet pair stores: lane 0 -> rows r0,r0+1; lane 2 -> r0+2,r0+3.
        fu hb; hb.f = h;
        fu hn; hn.f = __shfl(h, lane ^ 1, 64);
        if ((lane & ~2) == 0) {
            uint32x4 pkt;
            pkt.x = hb.u; pkt.y = (unsigned)(t + 1);
            pkt.z = hn.u; pkt.w = (unsigned)(t + 1);
            void* dp = (char*)slots + ((size_t)(t & 3) << 13) + ((size_t)(r0 + lane) << 3);
            asm volatile("global_store_dwordx4 %0, %1, off sc0 sc1"
                         :: "v"(dp), "v"(pkt) : "memory");
        }

        bx = bx_next;
    }
}

// ---------------------------------------------------------------------------
extern "C" void kernel_launch(void* const* d_in, const int* in_sizes, int n_in,
                              void* d_out, int out_size, void* d_ws, size_t ws_size,
                              hipStream_t stream)
{
    const float* x     = (const float*)d_in[0];  // [16384, 512]
    const float* h0    = (const float*)d_in[1];  // [1024]
    const float* A_raw = (const float*)d_in[2];  // [1024, 1024]
    const float* B     = (const float*)d_in[3];  // [1024, 512]
    const float* c     = (const float*)d_in[4];  // [1024]
    float* out = (float*)d_out;                  // [16384, 1024]
    unsigned long long* slots = (unsigned long long*)d_ws;  // 4 x 1024 x 8B

    dim3 gemm_grid(T_STEPS / 64, HD / 64);       // 256 x 16
    gemm_bx_kernel<<<gemm_grid, 256, 0, stream>>>(x, B, c, out);
    init_slots_kernel<<<1, HD, 0, stream>>>(slots, h0);
    rnn_scan_kernel<<<64, 256, 0, stream>>>(A_raw, out, slots);
}